// Round 10
// baseline (897.562 us; speedup 1.0000x reference)
//
#include <hip/hip_runtime.h>
#include <stdint.h>

typedef int v4i __attribute__((ext_vector_type(4)));

#define M_DIM 8192   // B*S = 2*4096
#define N_DIM 8192   // OUT
#define K_DIM 2048   // IN
#define RISKY_TAU 1e-4f
#define BUCKET_CAP 1024
#define SLOT 32768   // LDS buffer: A[256][64] 16KB + B[256][64] 16KB

// async global->LDS, 16B per lane (dest = wave-uniform base + lane*16)
#define ASYNC16(g, l) __builtin_amdgcn_global_load_lds(                        \
    (const __attribute__((address_space(1))) void*)(uintptr_t)(g),             \
    (__attribute__((address_space(3))) void*)(uint32_t)(uintptr_t)(l), 16, 0, 0)

// ---------------- 1) numpy-pairwise f32 sum of |w| ----------------
__global__ __launch_bounds__(256) void abssum_stage1(const float* __restrict__ w,
                                                     float* __restrict__ s1) {
  int b = blockIdx.x * 256 + threadIdx.x;  // 131072 leaf blocks of 128
  const float* p = w + (size_t)b * 128;
  float r[8];
#pragma unroll
  for (int j = 0; j < 8; j++) r[j] = fabsf(p[j]);
  for (int i = 8; i < 128; i += 8) {
#pragma unroll
    for (int j = 0; j < 8; j++) r[j] += fabsf(p[i + j]);
  }
  s1[b] = ((r[0] + r[1]) + (r[2] + r[3])) + ((r[4] + r[5]) + (r[6] + r[7]));
}

__global__ __launch_bounds__(256) void abssum_stage2(const float* __restrict__ s1,
                                                     float* __restrict__ s2) {
  int t = blockIdx.x * 256 + threadIdx.x;  // 4096 threads
  float v[32];
#pragma unroll
  for (int i = 0; i < 32; i++) v[i] = s1[t * 32 + i];
#pragma unroll
  for (int s = 1; s < 32; s *= 2) {
#pragma unroll
    for (int i = 0; i < 32; i += 2 * s) v[i] += v[i + s];
  }
  s2[t] = v[0];
}

__global__ __launch_bounds__(256) void gamma_stage3(const float* __restrict__ s2,
                                                    float* __restrict__ gp) {
  int t = threadIdx.x;  // 256 threads, one block
  float v[16];
#pragma unroll
  for (int i = 0; i < 16; i++) v[i] = s2[t * 16 + i];
#pragma unroll
  for (int s = 1; s < 16; s *= 2) {
#pragma unroll
    for (int i = 0; i < 16; i += 2 * s) v[i] += v[i + s];
  }
  __shared__ float sm[256];
  sm[t] = v[0];
  for (int s = 1; s < 256; s *= 2) {
    __syncthreads();
    if ((t & (2 * s - 1)) == 0) sm[t] += sm[t + s];
  }
  __syncthreads();
  if (t == 0) {
    float g = sm[0] * 0x1p-24f;  // /(8192*2048), exact pow2 scale
    gp[0] = fmaxf(g, 1e-5f);
  }
}

__global__ void zero_counts(int* __restrict__ counts) {
  counts[threadIdx.x] = 0;
}

// ---------------- 2) ternary weight quant + risky-midpoint detection ----------------
__global__ __launch_bounds__(256) void wq_kernel(const float4* __restrict__ w4,
                                                 const float* __restrict__ gp,
                                                 int* __restrict__ wq,
                                                 int* __restrict__ counts,
                                                 int* __restrict__ buckets) {
  int i = blockIdx.x * 256 + threadIdx.x;
  float g = gp[0];
  float4 v = w4[i];
  float e[4] = {v.x, v.y, v.z, v.w};
  int q[4];
#pragma unroll
  for (int c = 0; c < 4; c++) {
    q[c] = (int)rintf(fminf(fmaxf(e[c] / g, -1.0f), 1.0f));
    float t = fabsf(e[c]) / g;
    if (fabsf(t - 0.5f) < RISKY_TAU) {
      int flat = i * 4 + c;
      int n = flat >> 11;          // weight row (output col)
      int k = flat & 2047;
      int sgn_neg = (e[c] < 0.0f) ? 1 : 0;
      int sbit = (q[c] == 0) ? sgn_neg : (1 - sgn_neg);
      int b = n >> 7;
      int idx = atomicAdd(&counts[b], 1);
      if (idx < BUCKET_CAP)
        buckets[b * BUCKET_CAP + idx] = k | (n << 11) | (sbit << 24);
    }
  }
  wq[i] = (q[0] & 0xFF) | ((q[1] & 0xFF) << 8) | ((q[2] & 0xFF) << 16) | ((q[3] & 0xFF) << 24);
}

// ---------------- 3) fused LayerNorm + absmax int8 quant (one block per row) ----------------
__global__ __launch_bounds__(256) void lnq_kernel(const float* __restrict__ x,
                                                  const float* __restrict__ gp,
                                                  int8_t* __restrict__ xq,
                                                  float* __restrict__ scales) {
  const int row = blockIdx.x;
  const int t = threadIdx.x;
  const float4* xr = (const float4*)(x + (size_t)row * K_DIM);
  float4 a = xr[t];
  float4 b = xr[t + 256];
  double v[8] = {a.x, a.y, a.z, a.w, b.x, b.y, b.z, b.w};
  double s = 0.0, ss = 0.0;
#pragma unroll
  for (int i = 0; i < 8; i++) { s += v[i]; ss += v[i] * v[i]; }
  __shared__ double sm1[256], sm2[256];
  sm1[t] = s; sm2[t] = ss;
  __syncthreads();
  for (int off = 128; off > 0; off >>= 1) {
    if (t < off) { sm1[t] += sm1[t + off]; sm2[t] += sm2[t + off]; }
    __syncthreads();
  }
  double mu = sm1[0] * (1.0 / 2048.0);
  double var = sm2[0] * (1.0 / 2048.0) - mu * mu;  // biased variance
  double inv = 1.0 / sqrt(var + 1e-5);
  __syncthreads();
  double mx = 0.0;
#pragma unroll
  for (int i = 0; i < 8; i++) {
    v[i] = (v[i] - mu) * inv;
    double av = fabs(v[i]);
    if (av > mx) mx = av;
  }
  sm1[t] = mx;
  __syncthreads();
  for (int off = 128; off > 0; off >>= 1) {
    if (t < off) sm1[t] = fmax(sm1[t], sm1[t + off]);
    __syncthreads();
  }
  double eta = fmax(sm1[0], 1e-5);
  double r = 127.0 / eta;
  int q[8];
#pragma unroll
  for (int i = 0; i < 8; i++) {
    double qq = rint(v[i] * r);  // round-half-even, then clip
    qq = fmin(fmax(qq, -128.0), 127.0);
    q[i] = (int)qq;
  }
  int p0 = (q[0] & 0xFF) | ((q[1] & 0xFF) << 8) | ((q[2] & 0xFF) << 16) | ((q[3] & 0xFF) << 24);
  int p1 = (q[4] & 0xFF) | ((q[5] & 0xFF) << 8) | ((q[6] & 0xFF) << 16) | ((q[7] & 0xFF) << 24);
  int* orow = (int*)(xq + (size_t)row * K_DIM);
  orow[t] = p0;
  orow[t + 256] = p1;
  if (t == 0) scales[row] = (float)((double)gp[0] * eta * (1.0 / 127.0));
}

// ---------------- 4) int8 MFMA GEMM: 256x256 tile, 8 waves, BK=64, 2-phase dbuf ----------
// r8/r9-proven sync (stage-before-compute, ONE __syncthreads drain per K-step), scaled to
// wave tile 128x64 (85 OPS per LDS byte vs 64) so the matrix pipe, not LDS, is the longest
// pole: per CU per K-step MFMA ~1306cyc vs LDS ~1150cyc. 8 waves (2Mx4N), acc 8x4.
__global__ __launch_bounds__(512, 2) void gemm_i8_kernel(const int8_t* __restrict__ A,
                                                         const int8_t* __restrict__ B,
                                                         const float* __restrict__ scales,
                                                         const float* __restrict__ bias,
                                                         const int* __restrict__ counts,
                                                         const int* __restrict__ buckets,
                                                         float* __restrict__ C) {
  __shared__ alignas(16) int8_t lds[2 * SLOT];  // 64 KiB
  const int tid = threadIdx.x;
  const int wave = tid >> 6;   // 0..7
  const int lane = tid & 63;
  const int brow = blockIdx.y * 256;
  const int bcol = blockIdx.x * 256;

  // staging: per matrix 16 chunks of 1KB (16 rows x 64B); wave w stages chunks {2w,2w+1}.
  // lane -> row-in-chunk (lane>>2), slot (lane&3); source col XOR-swizzled by row&3.
  const int chunkr = lane >> 2;
  const int sl = lane & 3;
  const int8_t* gA[2];
  const int8_t* gB[2];
  int dA[2], dB[2];
#pragma unroll
  for (int c = 0; c < 2; c++) {
    int ch = wave * 2 + c;
    int r = ch * 16 + chunkr;
    int scol = ((sl ^ (r & 3)) << 4);
    gA[c] = A + (size_t)(brow + r) * K_DIM + scol;
    gB[c] = B + (size_t)(bcol + r) * K_DIM + scol;
    dA[c] = ch * 1024;           // wave-uniform LDS base (+lane*16 by HW)
    dB[c] = 16384 + ch * 1024;
  }

  // fragment read offsets (swizzled), buffer-relative
  const int wr = wave >> 2;    // 0..1  (M half)
  const int wc = wave & 3;     // 0..3  (N quarter)
  const int ks = lane >> 4;    // k-slot 0..3
  int aoff[8], boff[4];
#pragma unroll
  for (int m = 0; m < 8; m++) {
    int r = wr * 128 + m * 16 + (lane & 15);
    aoff[m] = r * 64 + ((ks ^ (r & 3)) << 4);
  }
#pragma unroll
  for (int n = 0; n < 4; n++) {
    int r = wc * 64 + n * 16 + (lane & 15);
    boff[n] = 16384 + r * 64 + ((ks ^ (r & 3)) << 4);
  }

  v4i acc[8][4];
  const v4i vzero = {0, 0, 0, 0};
#pragma unroll
  for (int m = 0; m < 8; m++)
#pragma unroll
    for (int n = 0; n < 4; n++) acc[m][n] = vzero;

  // prologue: stage tile 0 -> buf 0; drain
#pragma unroll
  for (int c = 0; c < 2; c++) {
    ASYNC16(gA[c], lds + dA[c]);
    ASYNC16(gB[c], lds + dB[c]);
  }
  __syncthreads();  // vmcnt(0): tile 0 landed

  int cur = 0;
  for (int t = 0; t < 32; ++t) {
    // issue next-tile staging first (hides under this tile's ds_read+MFMA)
    if (t < 31) {
      const int kt = (t + 1) * 64;
      const int sb = (cur ^ 1) * SLOT;
#pragma unroll
      for (int c = 0; c < 2; c++) {
        ASYNC16(gA[c] + kt, lds + sb + dA[c]);
        ASYNC16(gB[c] + kt, lds + sb + dB[c]);
      }
    }
    const int rb = cur * SLOT;
    v4i bf[4], af[8];
#pragma unroll
    for (int n = 0; n < 4; n++) bf[n] = *(const v4i*)(lds + rb + boff[n]);
#pragma unroll
    for (int m = 0; m < 8; m++) af[m] = *(const v4i*)(lds + rb + aoff[m]);
    __builtin_amdgcn_s_setprio(1);
#pragma unroll
    for (int m = 0; m < 8; m++)
#pragma unroll
      for (int n = 0; n < 4; n++)
        acc[m][n] = __builtin_amdgcn_mfma_i32_16x16x64_i8(af[m], bf[n], acc[m][n], 0, 0, 0);
    __builtin_amdgcn_s_setprio(0);
    __syncthreads();  // one drain per K-step: tile t+1 landed; ds_reads of buf done
    cur ^= 1;
  }

  // double accumulators (midpoint = odd integer), then apply risky corrections
#pragma unroll
  for (int m = 0; m < 8; m++)
#pragma unroll
    for (int n = 0; n < 4; n++) acc[m][n] = acc[m][n] + acc[m][n];

  const int crow0 = brow + wr * 128;
  const int ccol0 = bcol + wc * 64;

#define CORR(J)                                                                \
  {                                                                            \
    _Pragma("unroll") for (int m = 0; m < 8; m++) {                            \
      _Pragma("unroll") for (int r = 0; r < 4; r++) {                          \
        int grow = crow0 + m * 16 + ((lane >> 4) << 2) + r;                    \
        int xv = (int)A[(size_t)grow * K_DIM + k];                             \
        acc[m][J][r] += sv * xv;                                               \
      }                                                                        \
    }                                                                          \
  }

  {
    int bkt = (bcol + wc * 64) >> 7;  // 128-col bucket containing this wave's 64 cols
    int cnt = counts[bkt];
    if (cnt > BUCKET_CAP) cnt = BUCKET_CAP;
    const int* bk = buckets + bkt * BUCKET_CAP;
    for (int e = 0; e < cnt; ++e) {
      int word = bk[e];
      int k = word & 2047;
      int nc = (word >> 11) & 8191;
      int sv = ((word >> 24) & 1) ? -1 : 1;
      if (((nc >> 6) & 1) == (wc & 1) && (nc & 15) == (lane & 15)) {
        int j = (nc >> 4) & 3;
        switch (j) {
          case 0: CORR(0); break;
          case 1: CORR(1); break;
          case 2: CORR(2); break;
          case 3: CORR(3); break;
        }
      }
    }
  }
#undef CORR

  // epilogue: C[m][n] = (2*acc_corrected) * (scale_m/2) + bias[n]  (normal cached stores)
#pragma unroll
  for (int m = 0; m < 8; m++) {
#pragma unroll
    for (int r = 0; r < 4; r++) {
      int grow = crow0 + m * 16 + ((lane >> 4) << 2) + r;
      float sc = scales[grow] * 0.5f;
      float* crow = C + (size_t)grow * N_DIM;
#pragma unroll
      for (int n = 0; n < 4; n++) {
        int gcol = ccol0 + n * 16 + (lane & 15);
        crow[gcol] = (float)acc[m][n][r] * sc + bias[gcol];
      }
    }
  }
}

extern "C" void kernel_launch(void* const* d_in, const int* in_sizes, int n_in,
                              void* d_out, int out_size, void* d_ws, size_t ws_size,
                              hipStream_t stream) {
  const float* x = (const float*)d_in[0];
  const float* w = (const float*)d_in[1];
  const float* bias = (const float*)d_in[2];
  float* out = (float*)d_out;

  char* ws = (char*)d_ws;
  float* s1 = (float*)(ws);                          // 512 KiB
  float* s2 = (float*)(ws + 0x100000);               // 16 KiB
  float* gamma_f = (float*)(ws + 0x110000);          // 4 B
  float* scales = (float*)(ws + 0x120000);           // 32 KiB
  int* counts = (int*)(ws + 0x130000);               // 64 * 4 B
  int* buckets = (int*)(ws + 0x131000);              // 256 KiB
  int8_t* Aq = (int8_t*)(ws + 0x200000);                             // 16 MiB
  int8_t* Wq = (int8_t*)(ws + 0x200000 + (size_t)M_DIM * K_DIM);     // 16 MiB

  abssum_stage1<<<512, 256, 0, stream>>>(w, s1);
  abssum_stage2<<<16, 256, 0, stream>>>(s1, s2);
  gamma_stage3<<<1, 256, 0, stream>>>(s2, gamma_f);
  zero_counts<<<1, 64, 0, stream>>>(counts);
  wq_kernel<<<(N_DIM * K_DIM / 4 + 255) / 256, 256, 0, stream>>>(
      (const float4*)w, gamma_f, (int*)Wq, counts, buckets);
  lnq_kernel<<<M_DIM, 256, 0, stream>>>(x, gamma_f, Aq, scales);
  dim3 grid(N_DIM / 256, M_DIM / 256);
  gemm_i8_kernel<<<grid, 512, 0, stream>>>(Aq, Wq, scales, bias, counts, buckets, out);
}

// Round 11
// 286.969 us; speedup vs baseline: 3.1277x; 3.1277x over previous
//
#include <hip/hip_runtime.h>
#include <stdint.h>

typedef int v4i __attribute__((ext_vector_type(4)));

#define M_DIM 8192   // B*S = 2*4096
#define N_DIM 8192   // OUT
#define K_DIM 2048   // IN
#define RISKY_TAU 1e-4f
#define BUCKET_CAP 1024
#define SLOT 32768   // LDS buffer: A[256][64] 16KB + B[256][64] 16KB

// async global->LDS, 16B per lane (dest = wave-uniform base + lane*16)
#define ASYNC16(g, l) __builtin_amdgcn_global_load_lds(                        \
    (const __attribute__((address_space(1))) void*)(uintptr_t)(g),             \
    (__attribute__((address_space(3))) void*)(uint32_t)(uintptr_t)(l), 16, 0, 0)

// ---------------- 1) numpy-pairwise f32 sum of |w| ----------------
__global__ __launch_bounds__(256) void abssum_stage1(const float* __restrict__ w,
                                                     float* __restrict__ s1) {
  int b = blockIdx.x * 256 + threadIdx.x;  // 131072 leaf blocks of 128
  const float* p = w + (size_t)b * 128;
  float r[8];
#pragma unroll
  for (int j = 0; j < 8; j++) r[j] = fabsf(p[j]);
  for (int i = 8; i < 128; i += 8) {
#pragma unroll
    for (int j = 0; j < 8; j++) r[j] += fabsf(p[i + j]);
  }
  s1[b] = ((r[0] + r[1]) + (r[2] + r[3])) + ((r[4] + r[5]) + (r[6] + r[7]));
}

__global__ __launch_bounds__(256) void abssum_stage2(const float* __restrict__ s1,
                                                     float* __restrict__ s2) {
  int t = blockIdx.x * 256 + threadIdx.x;  // 4096 threads
  float v[32];
#pragma unroll
  for (int i = 0; i < 32; i++) v[i] = s1[t * 32 + i];
#pragma unroll
  for (int s = 1; s < 32; s *= 2) {
#pragma unroll
    for (int i = 0; i < 32; i += 2 * s) v[i] += v[i + s];
  }
  s2[t] = v[0];
}

__global__ __launch_bounds__(256) void gamma_stage3(const float* __restrict__ s2,
                                                    float* __restrict__ gp) {
  int t = threadIdx.x;  // 256 threads, one block
  float v[16];
#pragma unroll
  for (int i = 0; i < 16; i++) v[i] = s2[t * 16 + i];
#pragma unroll
  for (int s = 1; s < 16; s *= 2) {
#pragma unroll
    for (int i = 0; i < 16; i += 2 * s) v[i] += v[i + s];
  }
  __shared__ float sm[256];
  sm[t] = v[0];
  for (int s = 1; s < 256; s *= 2) {
    __syncthreads();
    if ((t & (2 * s - 1)) == 0) sm[t] += sm[t + s];
  }
  __syncthreads();
  if (t == 0) {
    float g = sm[0] * 0x1p-24f;  // /(8192*2048), exact pow2 scale
    gp[0] = fmaxf(g, 1e-5f);
  }
}

__global__ void zero_counts(int* __restrict__ counts) {
  counts[threadIdx.x] = 0;
}

// ---------------- 2) ternary weight quant + risky-midpoint detection ----------------
__global__ __launch_bounds__(256) void wq_kernel(const float4* __restrict__ w4,
                                                 const float* __restrict__ gp,
                                                 int* __restrict__ wq,
                                                 int* __restrict__ counts,
                                                 int* __restrict__ buckets) {
  int i = blockIdx.x * 256 + threadIdx.x;
  float g = gp[0];
  float4 v = w4[i];
  float e[4] = {v.x, v.y, v.z, v.w};
  int q[4];
#pragma unroll
  for (int c = 0; c < 4; c++) {
    q[c] = (int)rintf(fminf(fmaxf(e[c] / g, -1.0f), 1.0f));
    float t = fabsf(e[c]) / g;
    if (fabsf(t - 0.5f) < RISKY_TAU) {
      int flat = i * 4 + c;
      int n = flat >> 11;          // weight row (output col)
      int k = flat & 2047;
      int sgn_neg = (e[c] < 0.0f) ? 1 : 0;
      int sbit = (q[c] == 0) ? sgn_neg : (1 - sgn_neg);
      int b = n >> 7;
      int idx = atomicAdd(&counts[b], 1);
      if (idx < BUCKET_CAP)
        buckets[b * BUCKET_CAP + idx] = k | (n << 11) | (sbit << 24);
    }
  }
  wq[i] = (q[0] & 0xFF) | ((q[1] & 0xFF) << 8) | ((q[2] & 0xFF) << 16) | ((q[3] & 0xFF) << 24);
}

// ---------------- 3) fused LayerNorm + absmax int8 quant (one block per row) ----------------
__global__ __launch_bounds__(256) void lnq_kernel(const float* __restrict__ x,
                                                  const float* __restrict__ gp,
                                                  int8_t* __restrict__ xq,
                                                  float* __restrict__ scales) {
  const int row = blockIdx.x;
  const int t = threadIdx.x;
  const float4* xr = (const float4*)(x + (size_t)row * K_DIM);
  float4 a = xr[t];
  float4 b = xr[t + 256];
  double v[8] = {a.x, a.y, a.z, a.w, b.x, b.y, b.z, b.w};
  double s = 0.0, ss = 0.0;
#pragma unroll
  for (int i = 0; i < 8; i++) { s += v[i]; ss += v[i] * v[i]; }
  __shared__ double sm1[256], sm2[256];
  sm1[t] = s; sm2[t] = ss;
  __syncthreads();
  for (int off = 128; off > 0; off >>= 1) {
    if (t < off) { sm1[t] += sm1[t + off]; sm2[t] += sm2[t + off]; }
    __syncthreads();
  }
  double mu = sm1[0] * (1.0 / 2048.0);
  double var = sm2[0] * (1.0 / 2048.0) - mu * mu;  // biased variance
  double inv = 1.0 / sqrt(var + 1e-5);
  __syncthreads();
  double mx = 0.0;
#pragma unroll
  for (int i = 0; i < 8; i++) {
    v[i] = (v[i] - mu) * inv;
    double av = fabs(v[i]);
    if (av > mx) mx = av;
  }
  sm1[t] = mx;
  __syncthreads();
  for (int off = 128; off > 0; off >>= 1) {
    if (t < off) sm1[t] = fmax(sm1[t], sm1[t + off]);
    __syncthreads();
  }
  double eta = fmax(sm1[0], 1e-5);
  double r = 127.0 / eta;
  int q[8];
#pragma unroll
  for (int i = 0; i < 8; i++) {
    double qq = rint(v[i] * r);  // round-half-even, then clip
    qq = fmin(fmax(qq, -128.0), 127.0);
    q[i] = (int)qq;
  }
  int p0 = (q[0] & 0xFF) | ((q[1] & 0xFF) << 8) | ((q[2] & 0xFF) << 16) | ((q[3] & 0xFF) << 24);
  int p1 = (q[4] & 0xFF) | ((q[5] & 0xFF) << 8) | ((q[6] & 0xFF) << 16) | ((q[7] & 0xFF) << 24);
  int* orow = (int*)(xq + (size_t)row * K_DIM);
  orow[t] = p0;
  orow[t + 256] = p1;
  if (t == 0) scales[row] = (float)((double)gp[0] * eta * (1.0 / 127.0));
}

// ---------------- 4) int8 MFMA GEMM: 256x256 tile, 8 waves, BK=64, 2-phase dbuf ----------
// r10 structure + two fixes: (a) proven (r>>1)&3 swizzle (2-way max; r8/r9 measured 0
// conflicts); (b) column-major-within-XCD-slab block mapping: xcd=b&7 -> tile rows
// [4*xcd,4*xcd+4), idx=b>>3 column-major, so co-resident blocks on one XCD share 4 A-panels
// (2MB resident) and consume each B panel by 4 temporally-adjacent blocks (sliding window).
__global__ __launch_bounds__(512, 2) void gemm_i8_kernel(const int8_t* __restrict__ A,
                                                         const int8_t* __restrict__ B,
                                                         const float* __restrict__ scales,
                                                         const float* __restrict__ bias,
                                                         const int* __restrict__ counts,
                                                         const int* __restrict__ buckets,
                                                         float* __restrict__ C) {
  __shared__ alignas(16) int8_t lds[2 * SLOT];  // 64 KiB
  const int tid = threadIdx.x;
  const int wave = tid >> 6;   // 0..7
  const int lane = tid & 63;

  // XCD slab swizzle: 1024 blocks, xcd = b&7 owns tile rows [4*xcd, 4*xcd+4), col-major
  const int b = blockIdx.x;
  const int tr = (b & 7) * 4 + ((b >> 3) & 3);
  const int tc = b >> 5;
  const int brow = tr * 256;
  const int bcol = tc * 256;

  // staging: per matrix 16 chunks of 1KB (16 rows x 64B); wave w stages chunks {2w,2w+1}.
  // lane -> row-in-chunk (lane>>2), slot (lane&3); source col XOR-swizzled by (r>>1)&3.
  const int chunkr = lane >> 2;
  const int sl = lane & 3;
  const int8_t* gA[2];
  const int8_t* gB[2];
  int dA[2], dB[2];
#pragma unroll
  for (int c = 0; c < 2; c++) {
    int ch = wave * 2 + c;
    int r = ch * 16 + chunkr;
    int scol = ((sl ^ ((r >> 1) & 3)) << 4);
    gA[c] = A + (size_t)(brow + r) * K_DIM + scol;
    gB[c] = B + (size_t)(bcol + r) * K_DIM + scol;
    dA[c] = ch * 1024;           // wave-uniform LDS base (+lane*16 by HW)
    dB[c] = 16384 + ch * 1024;
  }

  // fragment read offsets (swizzled), buffer-relative
  const int wr = wave >> 2;    // 0..1  (M half)
  const int wc = wave & 3;     // 0..3  (N quarter)
  const int ks = lane >> 4;    // k-slot 0..3
  int aoff[8], boff[4];
#pragma unroll
  for (int m = 0; m < 8; m++) {
    int r = wr * 128 + m * 16 + (lane & 15);
    aoff[m] = r * 64 + ((ks ^ ((r >> 1) & 3)) << 4);
  }
#pragma unroll
  for (int n = 0; n < 4; n++) {
    int r = wc * 64 + n * 16 + (lane & 15);
    boff[n] = 16384 + r * 64 + ((ks ^ ((r >> 1) & 3)) << 4);
  }

  v4i acc[8][4];
  const v4i vzero = {0, 0, 0, 0};
#pragma unroll
  for (int m = 0; m < 8; m++)
#pragma unroll
    for (int n = 0; n < 4; n++) acc[m][n] = vzero;

  // prologue: stage tile 0 -> buf 0; drain
#pragma unroll
  for (int c = 0; c < 2; c++) {
    ASYNC16(gA[c], lds + dA[c]);
    ASYNC16(gB[c], lds + dB[c]);
  }
  __syncthreads();  // vmcnt(0): tile 0 landed

  int cur = 0;
  for (int t = 0; t < 32; ++t) {
    // issue next-tile staging first (hides under this tile's ds_read+MFMA)
    if (t < 31) {
      const int kt = (t + 1) * 64;
      const int sb = (cur ^ 1) * SLOT;
#pragma unroll
      for (int c = 0; c < 2; c++) {
        ASYNC16(gA[c] + kt, lds + sb + dA[c]);
        ASYNC16(gB[c] + kt, lds + sb + dB[c]);
      }
    }
    const int rb = cur * SLOT;
    v4i bf[4], af[8];
#pragma unroll
    for (int n = 0; n < 4; n++) bf[n] = *(const v4i*)(lds + rb + boff[n]);
#pragma unroll
    for (int m = 0; m < 8; m++) af[m] = *(const v4i*)(lds + rb + aoff[m]);
    __builtin_amdgcn_s_setprio(1);
#pragma unroll
    for (int m = 0; m < 8; m++)
#pragma unroll
      for (int n = 0; n < 4; n++)
        acc[m][n] = __builtin_amdgcn_mfma_i32_16x16x64_i8(af[m], bf[n], acc[m][n], 0, 0, 0);
    __builtin_amdgcn_s_setprio(0);
    __syncthreads();  // one drain per K-step: tile t+1 landed; ds_reads of buf done
    cur ^= 1;
  }

  // double accumulators (midpoint = odd integer), then apply risky corrections
#pragma unroll
  for (int m = 0; m < 8; m++)
#pragma unroll
    for (int n = 0; n < 4; n++) acc[m][n] = acc[m][n] + acc[m][n];

  const int crow0 = brow + wr * 128;
  const int ccol0 = bcol + wc * 64;

#define CORR(J)                                                                \
  {                                                                            \
    _Pragma("unroll") for (int m = 0; m < 8; m++) {                            \
      _Pragma("unroll") for (int r = 0; r < 4; r++) {                          \
        int grow = crow0 + m * 16 + ((lane >> 4) << 2) + r;                    \
        int xv = (int)A[(size_t)grow * K_DIM + k];                             \
        acc[m][J][r] += sv * xv;                                               \
      }                                                                        \
    }                                                                          \
  }

  {
    int bkt = (bcol + wc * 64) >> 7;  // 128-col bucket containing this wave's 64 cols
    int cnt = counts[bkt];
    if (cnt > BUCKET_CAP) cnt = BUCKET_CAP;
    const int* bk = buckets + bkt * BUCKET_CAP;
    for (int e = 0; e < cnt; ++e) {
      int word = bk[e];
      int k = word & 2047;
      int nc = (word >> 11) & 8191;
      int sv = ((word >> 24) & 1) ? -1 : 1;
      if (((nc >> 6) & 1) == (wc & 1) && (nc & 15) == (lane & 15)) {
        int j = (nc >> 4) & 3;
        switch (j) {
          case 0: CORR(0); break;
          case 1: CORR(1); break;
          case 2: CORR(2); break;
          case 3: CORR(3); break;
        }
      }
    }
  }
#undef CORR

  // epilogue: C[m][n] = (2*acc_corrected) * (scale_m/2) + bias[n]  (normal cached stores)
#pragma unroll
  for (int m = 0; m < 8; m++) {
#pragma unroll
    for (int r = 0; r < 4; r++) {
      int grow = crow0 + m * 16 + ((lane >> 4) << 2) + r;
      float sc = scales[grow] * 0.5f;
      float* crow = C + (size_t)grow * N_DIM;
#pragma unroll
      for (int n = 0; n < 4; n++) {
        int gcol = ccol0 + n * 16 + (lane & 15);
        crow[gcol] = (float)acc[m][n][r] * sc + bias[gcol];
      }
    }
  }
}

extern "C" void kernel_launch(void* const* d_in, const int* in_sizes, int n_in,
                              void* d_out, int out_size, void* d_ws, size_t ws_size,
                              hipStream_t stream) {
  const float* x = (const float*)d_in[0];
  const float* w = (const float*)d_in[1];
  const float* bias = (const float*)d_in[2];
  float* out = (float*)d_out;

  char* ws = (char*)d_ws;
  float* s1 = (float*)(ws);                          // 512 KiB
  float* s2 = (float*)(ws + 0x100000);               // 16 KiB
  float* gamma_f = (float*)(ws + 0x110000);          // 4 B
  float* scales = (float*)(ws + 0x120000);           // 32 KiB
  int* counts = (int*)(ws + 0x130000);               // 64 * 4 B
  int* buckets = (int*)(ws + 0x131000);              // 256 KiB
  int8_t* Aq = (int8_t*)(ws + 0x200000);                             // 16 MiB
  int8_t* Wq = (int8_t*)(ws + 0x200000 + (size_t)M_DIM * K_DIM);     // 16 MiB

  abssum_stage1<<<512, 256, 0, stream>>>(w, s1);
  abssum_stage2<<<16, 256, 0, stream>>>(s1, s2);
  gamma_stage3<<<1, 256, 0, stream>>>(s2, gamma_f);
  zero_counts<<<1, 64, 0, stream>>>(counts);
  wq_kernel<<<(N_DIM * K_DIM / 4 + 255) / 256, 256, 0, stream>>>(
      (const float4*)w, gamma_f, (int*)Wq, counts, buckets);
  lnq_kernel<<<M_DIM, 256, 0, stream>>>(x, gamma_f, Aq, scales);
  gemm_i8_kernel<<<1024, 512, 0, stream>>>(Aq, Wq, scales, bias, counts, buckets, out);
}

// Round 12
// 280.222 us; speedup vs baseline: 3.2030x; 1.0241x over previous
//
#include <hip/hip_runtime.h>
#include <stdint.h>

typedef int v4i __attribute__((ext_vector_type(4)));

#define M_DIM 8192   // B*S = 2*4096
#define N_DIM 8192   // OUT
#define K_DIM 2048   // IN
#define RISKY_TAU 1e-4f
#define BUCKET_CAP 1024
#define SLOT 32768   // LDS slot: A[256][64] 16KB + B[256][64] 16KB

// async global->LDS, 16B per lane (dest = wave-uniform base + lane*16)
#define ASYNC16(g, l) __builtin_amdgcn_global_load_lds(                        \
    (const __attribute__((address_space(1))) void*)(uintptr_t)(g),             \
    (__attribute__((address_space(3))) void*)(uint32_t)(uintptr_t)(l), 16, 0, 0)

// ---------------- 1) numpy-pairwise f32 sum of |w| ----------------
__global__ __launch_bounds__(256) void abssum_stage1(const float* __restrict__ w,
                                                     float* __restrict__ s1) {
  int b = blockIdx.x * 256 + threadIdx.x;  // 131072 leaf blocks of 128
  const float* p = w + (size_t)b * 128;
  float r[8];
#pragma unroll
  for (int j = 0; j < 8; j++) r[j] = fabsf(p[j]);
  for (int i = 8; i < 128; i += 8) {
#pragma unroll
    for (int j = 0; j < 8; j++) r[j] += fabsf(p[i + j]);
  }
  s1[b] = ((r[0] + r[1]) + (r[2] + r[3])) + ((r[4] + r[5]) + (r[6] + r[7]));
}

__global__ __launch_bounds__(256) void abssum_stage2(const float* __restrict__ s1,
                                                     float* __restrict__ s2) {
  int t = blockIdx.x * 256 + threadIdx.x;  // 4096 threads
  float v[32];
#pragma unroll
  for (int i = 0; i < 32; i++) v[i] = s1[t * 32 + i];
#pragma unroll
  for (int s = 1; s < 32; s *= 2) {
#pragma unroll
    for (int i = 0; i < 32; i += 2 * s) v[i] += v[i + s];
  }
  s2[t] = v[0];
}

__global__ __launch_bounds__(256) void gamma_stage3(const float* __restrict__ s2,
                                                    float* __restrict__ gp) {
  int t = threadIdx.x;  // 256 threads, one block
  float v[16];
#pragma unroll
  for (int i = 0; i < 16; i++) v[i] = s2[t * 16 + i];
#pragma unroll
  for (int s = 1; s < 16; s *= 2) {
#pragma unroll
    for (int i = 0; i < 16; i += 2 * s) v[i] += v[i + s];
  }
  __shared__ float sm[256];
  sm[t] = v[0];
  for (int s = 1; s < 256; s *= 2) {
    __syncthreads();
    if ((t & (2 * s - 1)) == 0) sm[t] += sm[t + s];
  }
  __syncthreads();
  if (t == 0) {
    float g = sm[0] * 0x1p-24f;  // /(8192*2048), exact pow2 scale
    gp[0] = fmaxf(g, 1e-5f);
  }
}

__global__ void zero_counts(int* __restrict__ counts) {
  counts[threadIdx.x] = 0;
}

// ---------------- 2) ternary weight quant + risky-midpoint detection ----------------
__global__ __launch_bounds__(256) void wq_kernel(const float4* __restrict__ w4,
                                                 const float* __restrict__ gp,
                                                 int* __restrict__ wq,
                                                 int* __restrict__ counts,
                                                 int* __restrict__ buckets) {
  int i = blockIdx.x * 256 + threadIdx.x;
  float g = gp[0];
  float4 v = w4[i];
  float e[4] = {v.x, v.y, v.z, v.w};
  int q[4];
#pragma unroll
  for (int c = 0; c < 4; c++) {
    q[c] = (int)rintf(fminf(fmaxf(e[c] / g, -1.0f), 1.0f));
    float t = fabsf(e[c]) / g;
    if (fabsf(t - 0.5f) < RISKY_TAU) {
      int flat = i * 4 + c;
      int n = flat >> 11;          // weight row (output col)
      int k = flat & 2047;
      int sgn_neg = (e[c] < 0.0f) ? 1 : 0;
      int sbit = (q[c] == 0) ? sgn_neg : (1 - sgn_neg);
      int b = n >> 7;
      int idx = atomicAdd(&counts[b], 1);
      if (idx < BUCKET_CAP)
        buckets[b * BUCKET_CAP + idx] = k | (n << 11) | (sbit << 24);
    }
  }
  wq[i] = (q[0] & 0xFF) | ((q[1] & 0xFF) << 8) | ((q[2] & 0xFF) << 16) | ((q[3] & 0xFF) << 24);
}

// ---------------- 3) fused LayerNorm + absmax int8 quant (one block per row) ----------------
__global__ __launch_bounds__(256) void lnq_kernel(const float* __restrict__ x,
                                                  const float* __restrict__ gp,
                                                  int8_t* __restrict__ xq,
                                                  float* __restrict__ scales) {
  const int row = blockIdx.x;
  const int t = threadIdx.x;
  const float4* xr = (const float4*)(x + (size_t)row * K_DIM);
  float4 a = xr[t];
  float4 b = xr[t + 256];
  double v[8] = {a.x, a.y, a.z, a.w, b.x, b.y, b.z, b.w};
  double s = 0.0, ss = 0.0;
#pragma unroll
  for (int i = 0; i < 8; i++) { s += v[i]; ss += v[i] * v[i]; }
  __shared__ double sm1[256], sm2[256];
  sm1[t] = s; sm2[t] = ss;
  __syncthreads();
  for (int off = 128; off > 0; off >>= 1) {
    if (t < off) { sm1[t] += sm1[t + off]; sm2[t] += sm2[t + off]; }
    __syncthreads();
  }
  double mu = sm1[0] * (1.0 / 2048.0);
  double var = sm2[0] * (1.0 / 2048.0) - mu * mu;  // biased variance
  double inv = 1.0 / sqrt(var + 1e-5);
  __syncthreads();
  double mx = 0.0;
#pragma unroll
  for (int i = 0; i < 8; i++) {
    v[i] = (v[i] - mu) * inv;
    double av = fabs(v[i]);
    if (av > mx) mx = av;
  }
  sm1[t] = mx;
  __syncthreads();
  for (int off = 128; off > 0; off >>= 1) {
    if (t < off) sm1[t] = fmax(sm1[t], sm1[t + off]);
    __syncthreads();
  }
  double eta = fmax(sm1[0], 1e-5);
  double r = 127.0 / eta;
  int q[8];
#pragma unroll
  for (int i = 0; i < 8; i++) {
    double qq = rint(v[i] * r);  // round-half-even, then clip
    qq = fmin(fmax(qq, -128.0), 127.0);
    q[i] = (int)qq;
  }
  int p0 = (q[0] & 0xFF) | ((q[1] & 0xFF) << 8) | ((q[2] & 0xFF) << 16) | ((q[3] & 0xFF) << 24);
  int p1 = (q[4] & 0xFF) | ((q[5] & 0xFF) << 8) | ((q[6] & 0xFF) << 16) | ((q[7] & 0xFF) << 24);
  int* orow = (int*)(xq + (size_t)row * K_DIM);
  orow[t] = p0;
  orow[t + 256] = p1;
  if (t == 0) scales[row] = (float)((double)gp[0] * eta * (1.0 / 127.0));
}

// ---------------- 4) int8 MFMA GEMM: 256x256, 8 waves, ring-3 LDS, counted vmcnt --------
// r11 locality (XCD slab swizzle, proven (r>>1)&3 LDS swizzle: FETCH 118MB, conflicts 0)
// + T3/T4 sync: 3-slot ring, stage tile t+2 per iter, s_waitcnt vmcnt(4) (never 0 in-loop)
// + raw s_barrier. RAW: tile t's 4 per-wave loads are the oldest outstanding at iter t ->
// vmcnt(4) drains exactly them; barrier publishes all waves' chunks. WAR: slot(t+2) ==
// slot(t-1); its ds_reads completed before each wave's iter-(t-1) MFMAs (lgkmcnt), which
// precede the iter-t barrier; stage is issued after that barrier.
__global__ __launch_bounds__(512) void gemm_i8_kernel(const int8_t* __restrict__ A,
                                                      const int8_t* __restrict__ B,
                                                      const float* __restrict__ scales,
                                                      const float* __restrict__ bias,
                                                      const int* __restrict__ counts,
                                                      const int* __restrict__ buckets,
                                                      float* __restrict__ C) {
  __shared__ alignas(16) int8_t lds[3 * SLOT];  // 96 KiB
  const int tid = threadIdx.x;
  const int wave = tid >> 6;   // 0..7
  const int lane = tid & 63;

  // XCD slab swizzle: 1024 blocks, xcd = b&7 owns tile rows [4*xcd, 4*xcd+4), col-major
  const int b = blockIdx.x;
  const int tr = (b & 7) * 4 + ((b >> 3) & 3);
  const int tc = b >> 5;
  const int brow = tr * 256;
  const int bcol = tc * 256;

  // staging: per matrix 16 chunks of 1KB (16 rows x 64B); wave w stages chunks {2w,2w+1}.
  // lane -> row-in-chunk (lane>>2), slot (lane&3); source col XOR-swizzled by (r>>1)&3.
  const int chunkr = lane >> 2;
  const int sl = lane & 3;
  const int8_t* gA[2];
  const int8_t* gB[2];
  int dA[2], dB[2];
#pragma unroll
  for (int c = 0; c < 2; c++) {
    int ch = wave * 2 + c;
    int r = ch * 16 + chunkr;
    int scol = ((sl ^ ((r >> 1) & 3)) << 4);
    gA[c] = A + (size_t)(brow + r) * K_DIM + scol;
    gB[c] = B + (size_t)(bcol + r) * K_DIM + scol;
    dA[c] = ch * 1024;           // wave-uniform LDS base (+lane*16 by HW)
    dB[c] = 16384 + ch * 1024;
  }

  // fragment read offsets (swizzled), slot-relative
  const int wr = wave >> 2;    // 0..1  (M half)
  const int wc = wave & 3;     // 0..3  (N quarter)
  const int ks = lane >> 4;    // k-slot 0..3
  int aoff[8], boff[4];
#pragma unroll
  for (int m = 0; m < 8; m++) {
    int r = wr * 128 + m * 16 + (lane & 15);
    aoff[m] = r * 64 + ((ks ^ ((r >> 1) & 3)) << 4);
  }
#pragma unroll
  for (int n = 0; n < 4; n++) {
    int r = wc * 64 + n * 16 + (lane & 15);
    boff[n] = 16384 + r * 64 + ((ks ^ ((r >> 1) & 3)) << 4);
  }

  v4i acc[8][4];
  const v4i vzero = {0, 0, 0, 0};
#pragma unroll
  for (int m = 0; m < 8; m++)
#pragma unroll
    for (int n = 0; n < 4; n++) acc[m][n] = vzero;

  // prologue: stage tile 0 -> slot 0, tile 1 -> slot 1 (4 loads/wave each)
#pragma unroll
  for (int c = 0; c < 2; c++) {
    ASYNC16(gA[c], lds + dA[c]);
    ASYNC16(gB[c], lds + dB[c]);
  }
#pragma unroll
  for (int c = 0; c < 2; c++) {
    ASYNC16(gA[c] + 64, lds + SLOT + dA[c]);
    ASYNC16(gB[c] + 64, lds + SLOT + dB[c]);
  }

  int rbase = 0;         // read slot base
  int sbase = 2 * SLOT;  // stage slot base
  for (int t = 0; t < 32; ++t) {
    // tile t landed (its 4 per-wave loads are the oldest outstanding)
    if (t < 31) asm volatile("s_waitcnt vmcnt(4)" ::: "memory");
    else        asm volatile("s_waitcnt vmcnt(0)" ::: "memory");
    __builtin_amdgcn_s_barrier();
    // stage tile t+2 into slot(t+2)%3 (lands >= 1 full K-step later)
    if (t < 30) {
      const int kt = (t + 2) * 64;
#pragma unroll
      for (int c = 0; c < 2; c++) {
        ASYNC16(gA[c] + kt, lds + sbase + dA[c]);
        ASYNC16(gB[c] + kt, lds + sbase + dB[c]);
      }
    }
    v4i bf[4], af[8];
#pragma unroll
    for (int n = 0; n < 4; n++) bf[n] = *(const v4i*)(lds + rbase + boff[n]);
#pragma unroll
    for (int m = 0; m < 8; m++) af[m] = *(const v4i*)(lds + rbase + aoff[m]);
    __builtin_amdgcn_s_setprio(1);
#pragma unroll
    for (int m = 0; m < 8; m++)
#pragma unroll
      for (int n = 0; n < 4; n++)
        acc[m][n] = __builtin_amdgcn_mfma_i32_16x16x64_i8(af[m], bf[n], acc[m][n], 0, 0, 0);
    __builtin_amdgcn_s_setprio(0);
    rbase = (rbase == 2 * SLOT) ? 0 : rbase + SLOT;
    sbase = (sbase == 2 * SLOT) ? 0 : sbase + SLOT;
  }

  // double accumulators (midpoint = odd integer), then apply risky corrections
#pragma unroll
  for (int m = 0; m < 8; m++)
#pragma unroll
    for (int n = 0; n < 4; n++) acc[m][n] = acc[m][n] + acc[m][n];

  const int crow0 = brow + wr * 128;
  const int ccol0 = bcol + wc * 64;

#define CORR(J)                                                                \
  {                                                                            \
    _Pragma("unroll") for (int m = 0; m < 8; m++) {                            \
      _Pragma("unroll") for (int r = 0; r < 4; r++) {                          \
        int grow = crow0 + m * 16 + ((lane >> 4) << 2) + r;                    \
        int xv = (int)A[(size_t)grow * K_DIM + k];                             \
        acc[m][J][r] += sv * xv;                                               \
      }                                                                        \
    }                                                                          \
  }

  {
    int bkt = (bcol + wc * 64) >> 7;  // 128-col bucket containing this wave's 64 cols
    int cnt = counts[bkt];
    if (cnt > BUCKET_CAP) cnt = BUCKET_CAP;
    const int* bk = buckets + bkt * BUCKET_CAP;
    for (int e = 0; e < cnt; ++e) {
      int word = bk[e];
      int k = word & 2047;
      int nc = (word >> 11) & 8191;
      int sv = ((word >> 24) & 1) ? -1 : 1;
      if (((nc >> 6) & 1) == (wc & 1) && (nc & 15) == (lane & 15)) {
        int j = (nc >> 4) & 3;
        switch (j) {
          case 0: CORR(0); break;
          case 1: CORR(1); break;
          case 2: CORR(2); break;
          case 3: CORR(3); break;
        }
      }
    }
  }
#undef CORR

  // epilogue: C[m][n] = (2*acc_corrected) * (scale_m/2) + bias[n]  (normal cached stores)
#pragma unroll
  for (int m = 0; m < 8; m++) {
#pragma unroll
    for (int r = 0; r < 4; r++) {
      int grow = crow0 + m * 16 + ((lane >> 4) << 2) + r;
      float sc = scales[grow] * 0.5f;
      float* crow = C + (size_t)grow * N_DIM;
#pragma unroll
      for (int n = 0; n < 4; n++) {
        int gcol = ccol0 + n * 16 + (lane & 15);
        crow[gcol] = (float)acc[m][n][r] * sc + bias[gcol];
      }
    }
  }
}

extern "C" void kernel_launch(void* const* d_in, const int* in_sizes, int n_in,
                              void* d_out, int out_size, void* d_ws, size_t ws_size,
                              hipStream_t stream) {
  const float* x = (const float*)d_in[0];
  const float* w = (const float*)d_in[1];
  const float* bias = (const float*)d_in[2];
  float* out = (float*)d_out;

  char* ws = (char*)d_ws;
  float* s1 = (float*)(ws);                          // 512 KiB
  float* s2 = (float*)(ws + 0x100000);               // 16 KiB
  float* gamma_f = (float*)(ws + 0x110000);          // 4 B
  float* scales = (float*)(ws + 0x120000);           // 32 KiB
  int* counts = (int*)(ws + 0x130000);               // 64 * 4 B
  int* buckets = (int*)(ws + 0x131000);              // 256 KiB
  int8_t* Aq = (int8_t*)(ws + 0x200000);                             // 16 MiB
  int8_t* Wq = (int8_t*)(ws + 0x200000 + (size_t)M_DIM * K_DIM);     // 16 MiB

  abssum_stage1<<<512, 256, 0, stream>>>(w, s1);
  abssum_stage2<<<16, 256, 0, stream>>>(s1, s2);
  gamma_stage3<<<1, 256, 0, stream>>>(s2, gamma_f);
  zero_counts<<<1, 64, 0, stream>>>(counts);
  wq_kernel<<<(N_DIM * K_DIM / 4 + 255) / 256, 256, 0, stream>>>(
      (const float4*)w, gamma_f, (int*)Wq, counts, buckets);
  lnq_kernel<<<M_DIM, 256, 0, stream>>>(x, gamma_f, Aq, scales);
  gemm_i8_kernel<<<1024, 512, 0, stream>>>(Aq, Wq, scales, bias, counts, buckets, out);
}